// Round 3
// baseline (138.591 us; speedup 1.0000x reference)
//
#include <hip/hip_runtime.h>
#include <stdint.h>

// Problem dims fixed by the reference: C=500, G=200, F=500, K=10, NF=5e6.
#define C_   500
#define G_   200
#define F_   500
#define K_   10
#define CG_  (C_ * G_)          // 100000
#define CGPB 125                // cg per bucket
#define NBUCK (CG_ / CGPB)      // 800
#define NVB  (NBUCK * 2)        // split histogram copies
#define RSTRIDE 504             // padded row stride in nibbles (63 words/row)
#define WPR  (RSTRIDE / 8)      // 63 words per cg row
#define NCW2 (CGPB * WPR + 1)   // 7876 words (+1 pad for uint4 zeroing)
#define TPB_P 1024
#define GRID_P 512              // = NBLK  (R1 proven config)
#define NBLK 512
#define TPB_B 512
#define CHUNK_MAX 10240         // >= ceil(NF/GRID_P) = 9766 (even)
#define FPT2 (CHUNK_MAX / TPB_P / 2) // 5 int2 pairs staged per thread
#define SLOT 40                 // fixed per-(block,bucket) slot capacity
#define OVF_CAP 16              // per-block overflow list capacity

// lgamma(n+1) for n = 0..15
__constant__ float LGF[16] = {
    0.0f, 0.0f, 0.69314718f, 1.79175947f, 3.17805383f, 4.78749174f,
    6.57925121f, 8.52516136f, 10.60460290f, 12.80182748f, 15.10441257f,
    17.50230785f, 19.98721450f, 22.55216385f, 25.19122118f, 27.89927138f
};

// Fused partition: utab prologue + histogram + single-wave scan + atomic-free
// LDS reorder + deterministic-slot bucket-major write-out. No global atomics.
// NOTE (R12 lesson): the LDS stage/reorder groups each (block,bucket) segment
// into ONE contiguous run at write-out; skipping it causes ~8x HBM write
// amplification and a 2.6x regression. Keep the reorder.
// NOTE (R2 lesson): segment-per-thread uint4 write-out REGRESSED — adjacent
// threads' destinations are 49KB apart -> 64 scattered stores/wave. The
// per-fragment loop below keeps adjacent threads writing adjacent bytes.
// NOTE (R1): hist/vstart use split-copy layout copy*NBUCK+b (both copies
// cover all 32 LDS banks; interleaved layout was 4-way bank-conflicted).
__global__ __launch_bounds__(TPB_P) void partition_kernel(
        const int* __restrict__ lci,
        const int* __restrict__ binix,
        const float* __restrict__ bc,
        const float* __restrict__ bw,
        const int* __restrict__ genes_oi,
        const float* __restrict__ dw,
        const float* __restrict__ cm,
        uint16_t* __restrict__ frag16,
        uint16_t* __restrict__ cnt16,
        uint32_t* __restrict__ ovfn,
        uint32_t* __restrict__ ovfe,
        float* __restrict__ u_tab,
        float* __restrict__ E,
        int NF, int chunk) {
    __shared__ uint32_t stage[CHUNK_MAX];   // 40 KB (packed, bucket-ordered)
    __shared__ uint32_t hist[NVB];          // 6.4 KB  [copy*NBUCK + b]
    __shared__ uint32_t vstart[NVB];        // 6.4 KB  [copy*NBUCK + b]
    __shared__ uint32_t sstart[NBUCK];      // 3.2 KB
    __shared__ float    psum[4];
    __shared__ uint32_t ovf_lds[OVF_CAP];
    __shared__ uint32_t oc;
    int tid = threadIdx.x;
    int blk = blockIdx.x;
    int copy = tid >> 9;                    // waves 0-7 -> copy 0, 8-15 -> 1
    int s0 = blk * chunk;
    int s1 = min(s0 + chunk, NF);
    int nloc = s1 - s0;                     // may be <= 0 for tail blocks

    for (int b = tid; b < NVB; b += TPB_P) hist[b] = 0;
    if (tid < 4) psum[tid] = 0.0f;
    if (tid == 0) oc = 0u;
    __syncthreads();                        // barrier A

    // --- utab prologue: 4 pairs per block, 256 threads (4 waves) per pair ---
    {
        int p = blk * 4 + (tid >> 8);
        if (p < K_ * G_) {
            int sub = tid & 255;
            int k = p / G_;
            int g = p - k * G_;
            float dwk = dw[k];
            float cmk = cm[k];
            const float* bcg = bc + (size_t)g * F_;
            const float* bwg = bw + (size_t)genes_oi[g] * F_;
            float* urow = u_tab + (size_t)p * F_;
            float u0 = dwk * bcg[sub] + bwg[sub] + cmk;
            urow[sub] = u0;
            float s = __expf(u0);
            int f1 = sub + 256;
            if (f1 < F_) {
                float u1 = dwk * bcg[f1] + bwg[f1] + cmk;
                urow[f1] = u1;
                s += __expf(u1);
            }
#pragma unroll
            for (int off = 32; off > 0; off >>= 1) s += __shfl_down(s, off);
            if ((tid & 63) == 0) atomicAdd(&psum[tid >> 8], s);
        }
    }

    // --- Phase 1: int2-vectorized fragment loads; histogram atomic = rank ---
    // chunk is forced even by the launcher, so (lci+s0)/(binix+s0) are
    // 8B-aligned and pair index math stays in-chunk. Tail guarded scalar.
    uint32_t my_pack[FPT2 * 2], my_rank[FPT2 * 2];
    const int2* lci2 = (const int2*)(lci + s0);
    const int2* bin2 = (const int2*)(binix + s0);
#pragma unroll
    for (int u = 0; u < FPT2; ++u) {
        int pi = u * TPB_P + tid;           // pair index within chunk
        int e0 = pi * 2;
        my_pack[2 * u]     = 0xFFFFFFFFu;
        my_pack[2 * u + 1] = 0xFFFFFFFFu;
        if (e0 + 1 < nloc) {
            int2 cg2 = lci2[pi];
            int2 f2  = bin2[pi];
            uint32_t b0  = (uint32_t)cg2.x / CGPB;          // magic-mul
            uint32_t lp0 = ((uint32_t)cg2.x - b0 * CGPB) * RSTRIDE + (uint32_t)f2.x;
            my_pack[2 * u] = (b0 << 16) | lp0;
            my_rank[2 * u] = atomicAdd(&hist[copy * NBUCK + b0], 1u);
            uint32_t b1  = (uint32_t)cg2.y / CGPB;
            uint32_t lp1 = ((uint32_t)cg2.y - b1 * CGPB) * RSTRIDE + (uint32_t)f2.y;
            my_pack[2 * u + 1] = (b1 << 16) | lp1;
            my_rank[2 * u + 1] = atomicAdd(&hist[copy * NBUCK + b1], 1u);
        } else if (e0 < nloc) {             // odd tail: single scalar element
            int cg = lci[s0 + e0];
            int f  = binix[s0 + e0];
            uint32_t b  = (uint32_t)cg / CGPB;
            uint32_t lp = ((uint32_t)cg - b * CGPB) * RSTRIDE + (uint32_t)f;
            my_pack[2 * u] = (b << 16) | lp;
            my_rank[2 * u] = atomicAdd(&hist[copy * NBUCK + b], 1u);
        }
    }
    __syncthreads();                        // barrier B

    // E write (psum complete), slot-count write, single-wave scan.
    if (tid < 4) {
        int p = blk * 4 + tid;
        if (p < K_ * G_) E[p] = psum[tid];
    }
    if (tid < 64) {
        int lane = tid;
        uint32_t loc[13];
        uint32_t run = 0;
#pragma unroll
        for (int q = 0; q < 13; ++q) {
            int b = lane * 13 + q;
            uint32_t n = (b < NBUCK) ? (hist[b] + hist[NBUCK + b]) : 0u;
            loc[q] = run;
            run += n;
        }
        uint32_t v = run;
        for (int d = 1; d < 64; d <<= 1) {
            uint32_t t = __shfl_up(v, d);
            if (lane >= d) v += t;
        }
        uint32_t excl = v - run;
#pragma unroll
        for (int q = 0; q < 13; ++q) {
            int b = lane * 13 + q;
            if (b < NBUCK) {
                uint32_t st = excl + loc[q];
                sstart[b] = st;
                vstart[b]         = st;
                vstart[NBUCK + b] = st + hist[b];
            }
        }
    } else if (tid < 64 + NBUCK) {
        int b = tid - 64;
        uint32_t n = hist[b] + hist[NBUCK + b];
        cnt16[(size_t)blk * NBUCK + b] = (uint16_t)min(n, (uint32_t)SLOT);
    }
    __syncthreads();

    // Phase 3: atomic-free scatter into bucket-ordered staging buffer.
#pragma unroll
    for (int u = 0; u < FPT2 * 2; ++u) {
        if (my_pack[u] != 0xFFFFFFFFu) {
            uint32_t bb = my_pack[u] >> 16;
            stage[vstart[copy * NBUCK + bb] + my_rank[u]] = my_pack[u];
        }
    }
    __syncthreads();

    // Phase 4: deterministic-slot bucket-major u16 write-out (grouped runs).
    for (int j = tid; j < nloc; j += TPB_P) {
        uint32_t v = stage[j];
        uint32_t b = v >> 16;
        uint32_t r = (uint32_t)j - sstart[b];   // rank within segment
        if (r < SLOT)
            frag16[((size_t)b * NBLK + blk) * SLOT + r] = (uint16_t)v;
        else {
            uint32_t o = atomicAdd(&oc, 1u);
            if (o < OVF_CAP) ovf_lds[o] = v;
        }
    }
    __syncthreads();
    if (tid == 0) ovfn[blk] = min(oc, (uint32_t)OVF_CAP);
    if (tid < OVF_CAP && tid < oc) ovfe[blk * OVF_CAP + tid] = ovf_lds[tid];
}

// One block per bucket. Dense contiguous slot read (uint4: 5 quads/segment)
// -> nibble counts (LDS atomics) + rare overflow entries.
// R3: scan phase restructured word-parallel: flatten (row, word) over all
// 512 threads, accumulate via LDS ds_add_f32 into rowsum[125]. Removes the
// per-row 6-step shfl chain + idle lanes of the old wave-per-row scan.
// Index map r = i % 125 puts lane-adjacent items on DIFFERENT rows (no
// same-address atomic serialization, 2-way bank alias only).
__global__ __launch_bounds__(TPB_B) void bucket_kernel(
        const uint16_t* __restrict__ frag16,
        const uint16_t* __restrict__ cnt16,
        const uint32_t* __restrict__ ovfn,
        const uint32_t* __restrict__ ovfe,
        const float* __restrict__ u_tab,
        const float* __restrict__ E,
        const int* __restrict__ labels,
        float* __restrict__ out) {
    __shared__ uint32_t cnt[NCW2];            // 7876 words = 31.5 KB
    __shared__ uint16_t cnts[NBLK];           // 1 KB
    __shared__ int pairidx[CGPB];
    __shared__ float rowsum[CGPB];
    int b = blockIdx.x;
    int tid = threadIdx.x;

    uint4* c4 = (uint4*)cnt;
    for (int w = tid; w < NCW2 / 4; w += TPB_B) c4[w] = make_uint4(0u, 0u, 0u, 0u);
    if (tid < CGPB) {
        int cg = b * CGPB + tid;
        int c = cg / G_;
        int g = cg - c * G_;
        pairidx[tid] = labels[c] * G_ + g;
        rowsum[tid] = 0.0f;
    }
    if (tid < NBLK) cnts[tid] = cnt16[(size_t)tid * NBUCK + b];
    __syncthreads();

    // Build: dense coalesced uint4 read of this bucket's slots.
    // Segment = SLOT(40) u16 = 80 B = 5 uint4 quads; quad q holds slots
    // [8q, 8q+8). Only quads with 8q < n are fetched.
    const uint4* fb4 = (const uint4*)(frag16 + (size_t)b * NBLK * SLOT);
    for (int i = tid; i < NBLK * 5; i += TPB_B) {      // 5 iterations
        uint32_t blk = (uint32_t)i / 5u;               // magic-mul
        uint32_t q   = (uint32_t)i - blk * 5u;
        int n  = (int)cnts[blk];
        int j0 = (int)q * 8;
        if (j0 < n) {
            uint4 four = fb4[i];
            int m = n - j0;                            // valid u16s in quad
            uint32_t wq[4] = {four.x, four.y, four.z, four.w};
#pragma unroll
            for (int t = 0; t < 8; ++t) {
                if (t < m) {
                    uint32_t l = (wq[t >> 1] >> ((t & 1) * 16)) & 0xFFFFu;
                    atomicAdd(&cnt[l >> 3], 1u << ((l & 7u) * 4u));
                }
            }
        }
    }
    // Overflow entries (expected ~0 total).
    if (tid < NBLK) {
        uint32_t on = ovfn[tid];
        for (uint32_t q = 0; q < on; ++q) {
            uint32_t e = ovfe[tid * OVF_CAP + q];
            if ((e >> 16) == (uint32_t)b) {
                uint32_t l = e & 0xFFFFu;
                atomicAdd(&cnt[l >> 3], 1u << ((l & 7u) * 4u));
            }
        }
    }
    __syncthreads();

    // Word-parallel scan: i -> (row r, word j); each nonzero count word does
    // one 32B u_tab gather (L2-resident) + 8 FMAs + one ds_add_f32.
    for (int i = tid; i < CGPB * 64; i += TPB_B) {     // 8000 items, ~16 iters
        int j = i / CGPB;                              // word 0..63 (magic)
        int r = i - j * CGPB;                          // row 0..124
        if (j < WPR) {
            uint32_t v = cnt[r * WPR + j];
            if (v) {
                const float4* up = (const float4*)(u_tab + (size_t)pairidx[r] * F_ + 8 * j);
                float4 ua = up[0];
                float4 ub = up[1];   // f >= 500 overreads hit zero nibbles
                float s = (float)( v        & 0xFu) * ua.x
                        + (float)((v >> 4)  & 0xFu) * ua.y
                        + (float)((v >> 8)  & 0xFu) * ua.z
                        + (float)((v >> 12) & 0xFu) * ua.w
                        + (float)((v >> 16) & 0xFu) * ub.x
                        + (float)((v >> 20) & 0xFu) * ub.y
                        + (float)((v >> 24) & 0xFu) * ub.z
                        + (float)((v >> 28)       ) * ub.w;
                if (v & 0xEEEEEEEEu) {        // some nibble >= 2: rare
#pragma unroll
                    for (int q = 0; q < 8; ++q)
                        s -= LGF[(v >> (q * 4)) & 0xFu];
                }
                atomicAdd(&rowsum[r], s);
            }
        }
    }
    __syncthreads();
    if (tid < CGPB) out[b * CGPB + tid] = rowsum[tid] - E[pairidx[tid]];
}

extern "C" void kernel_launch(void* const* d_in, const int* in_sizes, int n_in,
                              void* d_out, int out_size, void* d_ws, size_t ws_size,
                              hipStream_t stream) {
    const float* bc     = (const float*)d_in[0];
    const float* bw     = (const float*)d_in[1];
    const float* dw     = (const float*)d_in[2];
    const float* cm     = (const float*)d_in[3];
    const int* genes_oi = (const int*)d_in[4];
    const int* labels   = (const int*)d_in[5];
    const int* lci      = (const int*)d_in[6];
    const int* binix    = (const int*)d_in[7];
    float* out = (float*)d_out;

    const int NF = in_sizes[6];
    int chunk = (NF + GRID_P - 1) / GRID_P;   // 9766 for NF=5e6
    chunk = (chunk + 1) & ~1;                 // force even (int2 alignment)
    if (chunk > CHUNK_MAX) chunk = CHUNK_MAX;

    // ws: [frag16][cnt16][ovfn][ovfe][u_tab(+pad)][E]
    char* ws = (char*)d_ws;
    size_t off_cnt16 = ((size_t)NBUCK * NBLK * SLOT * sizeof(uint16_t) + 255) & ~(size_t)255;
    size_t off_ovfn  = (off_cnt16 + (size_t)NBLK * NBUCK * sizeof(uint16_t) + 255) & ~(size_t)255;
    size_t off_ovfe  = (off_ovfn + NBLK * sizeof(uint32_t) + 255) & ~(size_t)255;
    size_t off_utab  = (off_ovfe + (size_t)NBLK * OVF_CAP * sizeof(uint32_t) + 255) & ~(size_t)255;
    size_t off_E     = (off_utab + ((size_t)K_ * G_ * F_ + 16) * sizeof(float) + 255) & ~(size_t)255;

    uint16_t* frag16 = (uint16_t*)ws;
    uint16_t* cnt16  = (uint16_t*)(ws + off_cnt16);
    uint32_t* ovfn   = (uint32_t*)(ws + off_ovfn);
    uint32_t* ovfe   = (uint32_t*)(ws + off_ovfe);
    float*    u_tab  = (float*)(ws + off_utab);
    float*    E      = (float*)(ws + off_E);

    partition_kernel<<<GRID_P, TPB_P, 0, stream>>>(
        lci, binix, bc, bw, genes_oi, dw, cm,
        frag16, cnt16, ovfn, ovfe, u_tab, E, NF, chunk);

    bucket_kernel<<<NBUCK, TPB_B, 0, stream>>>(
        frag16, cnt16, ovfn, ovfe, u_tab, E, labels, out);
}

// Round 5
// 126.292 us; speedup vs baseline: 1.0974x; 1.0974x over previous
//
#include <hip/hip_runtime.h>
#include <stdint.h>

// Problem dims fixed by the reference: C=500, G=200, F=500, K=10, NF=5e6.
#define C_   500
#define G_   200
#define F_   500
#define K_   10
#define CG_  (C_ * G_)          // 100000
#define CGPB 125                // cg per bucket (cgl*504+f must fit u16)
#define NBUCK (CG_ / CGPB)      // 800
#define RSTRIDE 504             // padded row stride in nibbles (63 words/row)
#define WPR  (RSTRIDE / 8)      // 63 words per cg row
#define NCW2 (CGPB * WPR + 1)   // 7876 words (/4 exact for uint4 zeroing)
#define TPB_P 1024
#define GRID_P 512              // = NBLK; 2 blocks/CU
#define NBLK 512
#define TPB_B 512
#define CHUNK_MAX 10240         // >= ceil(NF/GRID_P) = 9766 (even)
#define FPT2 (CHUNK_MAX / TPB_P / 2) // 5 int2 pairs per thread
#define SLOT 32                 // slots/segment: 64B = 4 aligned sectors.
                                // lambda=12.2 -> P(n>32)~6e-7/seg, ~0.3
                                // overflows/run, handled by ovf path.
#define OVF_CAP 32              // per-block overflow list capacity

// lgamma(n+1) for n = 0..15
__constant__ float LGF[16] = {
    0.0f, 0.0f, 0.69314718f, 1.79175947f, 3.17805383f, 4.78749174f,
    6.57925121f, 8.52516136f, 10.60460290f, 12.80182748f, 15.10441257f,
    17.50230785f, 19.98721450f, 22.55216385f, 25.19122118f, 27.89927138f
};

// R5 single-pass partition: utab prologue + direct-slot LDS staging.
// rank atomic gives the FINAL slot; payload u16 goes straight to
// smem16[b*SLOT+r]. The LDS slot array IS the reorder (R12 grouping kept);
// write-out is a bounded uint4 copy (full 64B sectors, no RMW).
// Deletes: phase-3 scatter, prefix scan, per-fragment store addressing,
// 3 of 5 barriers. ~11 insts/fragment vs ~20 (partition was issue-bound).
// NOTE (R2): segment-per-thread scattered stores regressed; here adjacent
// lanes write adjacent quads of the same 64B segment. NOTE (R4): no
// cooperative launch, static LDS < 64KB.
__global__ __launch_bounds__(TPB_P) void partition_kernel(
        const int* __restrict__ lci,
        const int* __restrict__ binix,
        const float* __restrict__ bc,
        const float* __restrict__ bw,
        const int* __restrict__ genes_oi,
        const float* __restrict__ dw,
        const float* __restrict__ cm,
        uint16_t* __restrict__ frag16,
        uint16_t* __restrict__ cnt16,
        uint32_t* __restrict__ ovfn,
        uint32_t* __restrict__ ovfe,
        float* __restrict__ u_tab,
        float* __restrict__ E,
        int NF, int chunk) {
    __shared__ uint16_t smem16[NBUCK * SLOT];  // 50 KB slot staging
    __shared__ uint32_t hist[NBUCK];           // 3.2 KB
    __shared__ float    psum[4];
    __shared__ uint32_t ovf_lds[OVF_CAP];
    __shared__ uint32_t oc;
    int tid = threadIdx.x;
    int blk = blockIdx.x;
    int s0 = blk * chunk;
    int s1 = min(s0 + chunk, NF);
    int nloc = s1 - s0;

    if (tid < NBUCK) hist[tid] = 0;
    if (tid < 4) psum[tid] = 0.0f;
    if (tid == 0) oc = 0u;
    __syncthreads();                           // barrier A

    // --- utab prologue: 4 pairs per block, 256 threads per pair ---
    {
        int p = blk * 4 + (tid >> 8);
        if (p < K_ * G_) {
            int sub = tid & 255;
            int k = p / G_;
            int g = p - k * G_;
            float dwk = dw[k];
            float cmk = cm[k];
            const float* bcg = bc + (size_t)g * F_;
            const float* bwg = bw + (size_t)genes_oi[g] * F_;
            float* urow = u_tab + (size_t)p * F_;
            float u0 = dwk * bcg[sub] + bwg[sub] + cmk;
            urow[sub] = u0;
            float s = __expf(u0);
            int f1 = sub + 256;
            if (f1 < F_) {
                float u1 = dwk * bcg[f1] + bwg[f1] + cmk;
                urow[f1] = u1;
                s += __expf(u1);
            }
#pragma unroll
            for (int off = 32; off > 0; off >>= 1) s += __shfl_down(s, off);
            if ((tid & 63) == 0) atomicAdd(&psum[tid >> 8], s);
        }
    }

    // --- Phase 1: int2 loads; rank atomic -> direct LDS slot write ---
    const int2* lci2 = (const int2*)(lci + s0);
    const int2* bin2 = (const int2*)(binix + s0);
#pragma unroll
    for (int u = 0; u < FPT2; ++u) {
        int pi = u * TPB_P + tid;              // pair index within chunk
        int e0 = pi * 2;
        if (e0 + 1 < nloc) {
            int2 cg2 = lci2[pi];
            int2 f2  = bin2[pi];
            {
                uint32_t b  = (uint32_t)cg2.x / CGPB;          // magic-mul
                uint32_t lp = ((uint32_t)cg2.x - b * CGPB) * RSTRIDE + (uint32_t)f2.x;
                uint32_t r  = atomicAdd(&hist[b], 1u);
                if (r < SLOT) smem16[b * SLOT + r] = (uint16_t)lp;
                else {
                    uint32_t o = atomicAdd(&oc, 1u);
                    if (o < OVF_CAP) ovf_lds[o] = (b << 16) | lp;
                }
            }
            {
                uint32_t b  = (uint32_t)cg2.y / CGPB;
                uint32_t lp = ((uint32_t)cg2.y - b * CGPB) * RSTRIDE + (uint32_t)f2.y;
                uint32_t r  = atomicAdd(&hist[b], 1u);
                if (r < SLOT) smem16[b * SLOT + r] = (uint16_t)lp;
                else {
                    uint32_t o = atomicAdd(&oc, 1u);
                    if (o < OVF_CAP) ovf_lds[o] = (b << 16) | lp;
                }
            }
        } else if (e0 < nloc) {                // odd tail: single scalar
            int cg = lci[s0 + e0];
            int f  = binix[s0 + e0];
            uint32_t b  = (uint32_t)cg / CGPB;
            uint32_t lp = ((uint32_t)cg - b * CGPB) * RSTRIDE + (uint32_t)f;
            uint32_t r  = atomicAdd(&hist[b], 1u);
            if (r < SLOT) smem16[b * SLOT + r] = (uint16_t)lp;
            else {
                uint32_t o = atomicAdd(&oc, 1u);
                if (o < OVF_CAP) ovf_lds[o] = (b << 16) | lp;
            }
        }
    }
    __syncthreads();                           // barrier B

    // E write, coalesced cnt16 write.
    if (tid < 4) {
        int p = blk * 4 + tid;
        if (p < K_ * G_) E[p] = psum[tid];
    }
    if (tid < NBUCK)
        cnt16[(size_t)blk * NBUCK + tid] = (uint16_t)min(hist[tid], (uint32_t)SLOT);

    // Write-out: uint4 copy of occupied quads. Segment = 64B = 4 quads;
    // quad q holds slots [8q, 8q+8). Lanes of one wave cover 16 segments,
    // 4 lanes per segment write one full contiguous 64B sector.
    const uint4* s4 = (const uint4*)smem16;
    for (int i = tid; i < NBUCK * 4; i += TPB_P) {
        int seg = i >> 2;
        int q   = i & 3;
        uint32_t n = min(hist[seg], (uint32_t)SLOT);
        if ((uint32_t)(q * 8) < n) {
            uint4* dst = (uint4*)(frag16 + ((size_t)seg * NBLK + blk) * SLOT);
            dst[q] = s4[i];
        }
    }

    if (tid == 0) ovfn[blk] = min(oc, (uint32_t)OVF_CAP);
    if (tid < OVF_CAP && tid < oc) ovfe[blk * OVF_CAP + tid] = ovf_lds[tid];
}

// One block per bucket. Dense contiguous slot read (uint4: 4 quads/segment)
// -> nibble counts (LDS atomics) + rare overflow entries, then dense scan:
// wave-per-row, coalesced u-row float4 pairs (R3 lesson: word-parallel scan
// breaks u_tab coalescing and regressed), lgamma LUT only when nibble>=2.
__global__ __launch_bounds__(TPB_B) void bucket_kernel(
        const uint16_t* __restrict__ frag16,
        const uint16_t* __restrict__ cnt16,
        const uint32_t* __restrict__ ovfn,
        const uint32_t* __restrict__ ovfe,
        const float* __restrict__ u_tab,
        const float* __restrict__ E,
        const int* __restrict__ labels,
        float* __restrict__ out) {
    __shared__ uint32_t cnt[NCW2];            // 7876 words = 31.5 KB
    __shared__ uint16_t cnts[NBLK];           // 1 KB
    __shared__ int pairidx[CGPB];
    int b = blockIdx.x;
    int tid = threadIdx.x;

    uint4* c4 = (uint4*)cnt;
    for (int w = tid; w < NCW2 / 4; w += TPB_B) c4[w] = make_uint4(0u, 0u, 0u, 0u);
    if (tid < CGPB) {
        int cg = b * CGPB + tid;
        int c = cg / G_;
        int g = cg - c * G_;
        pairidx[tid] = labels[c] * G_ + g;
    }
    if (tid < NBLK) cnts[tid] = cnt16[(size_t)tid * NBUCK + b];
    __syncthreads();

    // Build: dense coalesced uint4 read of this bucket's slots.
    // Segment = SLOT(32) u16 = 64 B = 4 quads; quad q holds slots [8q,8q+8).
    const uint4* fb4 = (const uint4*)(frag16 + (size_t)b * NBLK * SLOT);
    for (int i = tid; i < NBLK * 4; i += TPB_B) {      // 4 iterations
        uint32_t blkq = (uint32_t)i >> 2;
        uint32_t q    = (uint32_t)i & 3u;
        int n  = (int)cnts[blkq];
        int j0 = (int)q * 8;
        if (j0 < n) {
            uint4 four = fb4[i];
            int m = n - j0;                            // valid u16s in quad
            uint32_t wq[4] = {four.x, four.y, four.z, four.w};
#pragma unroll
            for (int t = 0; t < 8; ++t) {
                if (t < m) {
                    uint32_t l = (wq[t >> 1] >> ((t & 1) * 16)) & 0xFFFFu;
                    atomicAdd(&cnt[l >> 3], 1u << ((l & 7u) * 4u));
                }
            }
        }
    }
    // Overflow entries (expected ~0 total).
    if (tid < NBLK) {
        uint32_t on = ovfn[tid];
        for (uint32_t q = 0; q < on; ++q) {
            uint32_t e = ovfe[tid * OVF_CAP + q];
            if ((e >> 16) == (uint32_t)b) {
                uint32_t l = e & 0xFFFFu;
                atomicAdd(&cnt[l >> 3], 1u << ((l & 7u) * 4u));
            }
        }
    }
    __syncthreads();

    int wave = tid >> 6, lane = tid & 63;
    for (int r = wave; r < CGPB; r += (TPB_B / 64)) {
        float s = 0.0f;
        if (lane < WPR) {
            uint32_t v = cnt[r * WPR + lane];
            if (v) {
                const float4* up = (const float4*)(u_tab + (size_t)pairidx[r] * F_ + 8 * lane);
                float4 ua = up[0];
                float4 ub = up[1];   // f >= 500 overreads hit zero nibbles
                s += (float)( v        & 0xFu) * ua.x
                   + (float)((v >> 4)  & 0xFu) * ua.y
                   + (float)((v >> 8)  & 0xFu) * ua.z
                   + (float)((v >> 12) & 0xFu) * ua.w
                   + (float)((v >> 16) & 0xFu) * ub.x
                   + (float)((v >> 20) & 0xFu) * ub.y
                   + (float)((v >> 24) & 0xFu) * ub.z
                   + (float)((v >> 28)       ) * ub.w;
                if (v & 0xEEEEEEEEu) {        // some nibble >= 2: rare
#pragma unroll
                    for (int q = 0; q < 8; ++q)
                        s -= LGF[(v >> (q * 4)) & 0xFu];
                }
            }
        }
#pragma unroll
        for (int off = 32; off > 0; off >>= 1) s += __shfl_down(s, off);
        if (lane == 0) out[b * CGPB + r] = s - E[pairidx[r]];
    }
}

extern "C" void kernel_launch(void* const* d_in, const int* in_sizes, int n_in,
                              void* d_out, int out_size, void* d_ws, size_t ws_size,
                              hipStream_t stream) {
    const float* bc     = (const float*)d_in[0];
    const float* bw     = (const float*)d_in[1];
    const float* dw     = (const float*)d_in[2];
    const float* cm     = (const float*)d_in[3];
    const int* genes_oi = (const int*)d_in[4];
    const int* labels   = (const int*)d_in[5];
    const int* lci      = (const int*)d_in[6];
    const int* binix    = (const int*)d_in[7];
    float* out = (float*)d_out;

    const int NF = in_sizes[6];
    int chunk = (NF + GRID_P - 1) / GRID_P;   // 9766 for NF=5e6
    chunk = (chunk + 1) & ~1;                 // force even (int2 alignment)
    if (chunk > CHUNK_MAX) chunk = CHUNK_MAX;

    // ws: [frag16][cnt16][ovfn][ovfe][u_tab(+pad)][E]
    char* ws = (char*)d_ws;
    size_t off_cnt16 = ((size_t)NBUCK * NBLK * SLOT * sizeof(uint16_t) + 255) & ~(size_t)255;
    size_t off_ovfn  = (off_cnt16 + (size_t)NBLK * NBUCK * sizeof(uint16_t) + 255) & ~(size_t)255;
    size_t off_ovfe  = (off_ovfn + NBLK * sizeof(uint32_t) + 255) & ~(size_t)255;
    size_t off_utab  = (off_ovfe + (size_t)NBLK * OVF_CAP * sizeof(uint32_t) + 255) & ~(size_t)255;
    size_t off_E     = (off_utab + ((size_t)K_ * G_ * F_ + 16) * sizeof(float) + 255) & ~(size_t)255;

    uint16_t* frag16 = (uint16_t*)ws;
    uint16_t* cnt16  = (uint16_t*)(ws + off_cnt16);
    uint32_t* ovfn   = (uint32_t*)(ws + off_ovfn);
    uint32_t* ovfe   = (uint32_t*)(ws + off_ovfe);
    float*    u_tab  = (float*)(ws + off_utab);
    float*    E      = (float*)(ws + off_E);

    partition_kernel<<<GRID_P, TPB_P, 0, stream>>>(
        lci, binix, bc, bw, genes_oi, dw, cm,
        frag16, cnt16, ovfn, ovfe, u_tab, E, NF, chunk);

    bucket_kernel<<<NBUCK, TPB_B, 0, stream>>>(
        frag16, cnt16, ovfn, ovfe, u_tab, E, labels, out);
}